// Round 11
// baseline (2480.189 us; speedup 1.0000x reference)
//
#include <hip/hip_runtime.h>
#include <hip/hip_bf16.h>
#include <math.h>

#define B_   8
#define N_   256
#define L_   6
#define D_   512
#define NT_  2048   // B_*N_
#define HID_ 2048

typedef __attribute__((ext_vector_type(4))) float f32x4;
typedef __attribute__((ext_vector_type(8))) short bf16x8;

struct bf16x4s { __hip_bfloat16 x, y, z, w; };

__device__ __forceinline__ bf16x4s to_bf4(float a, float b, float c, float d) {
    bf16x4s r;
    r.x = __float2bfloat16(a); r.y = __float2bfloat16(b);
    r.z = __float2bfloat16(c); r.w = __float2bfloat16(d);
    return r;
}

__device__ __forceinline__ float bf_to_f(unsigned short u) {
    union { unsigned int i; float f; } c;
    c.i = ((unsigned int)u) << 16;
    return c.f;
}

__device__ __forceinline__ void gload16(const void* g, void* l) {
    __builtin_amdgcn_global_load_lds(
        (const __attribute__((address_space(1))) int*)g,
        (__attribute__((address_space(3))) int*)l, 16, 0, 0);
}

__device__ __forceinline__ float gelu_exact(float v) {
    return 0.5f * v * (1.0f + erff(v * 0.70710678118654752f));
}

// ---------------------------------------------------------------------------
// 8-phase 256x256 FF GEMM (guide template, m201-style), BK=64, 512 thr =
// 8 waves (2M x 4N), per-wave 128x64 split into 4 quadrants of 64x32.
// LDS: 2 K-tile buffers x {A,B} x 2 halves x (128x64 bf16) = 128 KB.
// Per tile t (buf t&1): p1(qm0,qn0) stages A1(t+1); p2(0,1) stages A0(t+2);
// p3(1,0) stages B0(t+2); p4(1,1) stages B1(t+2) + vmcnt(6) (3 half-tiles
// in flight). Slot safety: every staged slot's reads were issued >=1 phase
// earlier and drained by that phase's lgkmcnt(0)+barrier. Prologue: 7
// half-tiles, vmcnt(6), barrier. XOR swizzle slot^=(row&7) pre-swizzled
// global src + swizzled ds_read (rule #21c). XCD swizzle (nwg%8==0).
// ---------------------------------------------------------------------------
template<typename CT, bool GELU>
__global__ __launch_bounds__(512, 2) void gemm_ff8(
    const __hip_bfloat16* __restrict__ A1p, int lda1, long az1,
    const __hip_bfloat16* __restrict__ A2p, int lda2, long az2, int zsplit,
    const __hip_bfloat16* __restrict__ B, int ldb, long bz,
    CT* __restrict__ C, int ldc, long cz, int K)
{
    __shared__ short SA[2][2][128 * 64];
    __shared__ short SB[2][2][128 * 64];

    const int tid = threadIdx.x;
    const int wv = tid >> 6, lane = tid & 63;
    const int wr = wv >> 2, wc = wv & 3;

    const int gx = gridDim.x, gy = gridDim.y;
    const int nwg = gx * gy * gridDim.z;
    int lid = (blockIdx.z * gy + blockIdx.y) * gx + blockIdx.x;
    lid = (lid & 7) * (nwg >> 3) + (lid >> 3);
    const int bx = lid % gx, by = (lid / gx) % gy, bzz = lid / (gx * gy);

    const __hip_bfloat16* A;
    int lda;
    if (bzz < zsplit) { A = A1p + (long)bzz * az1;            lda = lda1; }
    else              { A = A2p + (long)(bzz - zsplit) * az2; lda = lda2; }
    B += (long)bzz * bz;  C += (long)bzz * cz;
    const int m0 = by * 256, n0 = bx * 256;

    const int srow = tid >> 3, sslot = tid & 7;   // staging map
    const int fr = lane & 15, k4 = lane >> 4;     // fragment map

    f32x4 acc[2][2][4][2] = {};
    bf16x8 af[4][2];        // A fragments of current qm (i, ks)
    bf16x8 bf[2][2][2];     // B fragments (qn, j, ks) — both halves live

#define STAGE_HALF(S, P, LD, BR, BUF, HF, K0)                                 \
    {                                                                         \
        _Pragma("unroll")                                                     \
        for (int i_ = 0; i_ < 2; ++i_) {                                      \
            const int r_ = srow + i_ * 64;                                    \
            const int gs_ = sslot ^ (r_ & 7);                                 \
            gload16(P + (long)((BR) + r_) * (LD) + (K0) + gs_ * 8,            \
                    &S[BUF][HF][(i_ * 64 + wv * 8) * 64]);                    \
        }                                                                     \
    }

#define READ_A(QM, BUF)                                                       \
    {                                                                         \
        _Pragma("unroll")                                                     \
        for (int i_ = 0; i_ < 4; ++i_) {                                      \
            const int r_ = wr * 64 + i_ * 16 + fr;                            \
            af[i_][0] = *(const bf16x8*)&SA[BUF][QM][r_ * 64 + ((k4)     ^ (r_ & 7)) * 8]; \
            af[i_][1] = *(const bf16x8*)&SA[BUF][QM][r_ * 64 + ((4 + k4) ^ (r_ & 7)) * 8]; \
        }                                                                     \
    }

#define READ_B(QN, BUF)                                                       \
    {                                                                         \
        _Pragma("unroll")                                                     \
        for (int j_ = 0; j_ < 2; ++j_) {                                      \
            const int r_ = wc * 32 + j_ * 16 + fr;                            \
            bf[QN][j_][0] = *(const bf16x8*)&SB[BUF][QN][r_ * 64 + ((k4)     ^ (r_ & 7)) * 8]; \
            bf[QN][j_][1] = *(const bf16x8*)&SB[BUF][QN][r_ * 64 + ((4 + k4) ^ (r_ & 7)) * 8]; \
        }                                                                     \
    }

#define MFMA_PHASE(QM, QN)                                                    \
    __builtin_amdgcn_s_barrier();                                             \
    asm volatile("s_waitcnt lgkmcnt(0)" ::: "memory");                        \
    __builtin_amdgcn_sched_barrier(0);                                        \
    __builtin_amdgcn_s_setprio(1);                                            \
    {                                                                         \
        _Pragma("unroll")                                                     \
        for (int i_ = 0; i_ < 4; ++i_)                                        \
            _Pragma("unroll")                                                 \
            for (int j_ = 0; j_ < 2; ++j_) {                                  \
                acc[QM][QN][i_][j_] = __builtin_amdgcn_mfma_f32_16x16x32_bf16(\
                    af[i_][0], bf[QN][j_][0], acc[QM][QN][i_][j_], 0, 0, 0);  \
                acc[QM][QN][i_][j_] = __builtin_amdgcn_mfma_f32_16x16x32_bf16(\
                    af[i_][1], bf[QN][j_][1], acc[QM][QN][i_][j_], 0, 0, 0);  \
            }                                                                 \
    }                                                                         \
    __builtin_amdgcn_s_setprio(0);

    // ---- prologue: 7 half-tiles (tile 0 complete + A0,B0,B1 of tile 1) ----
    STAGE_HALF(SA, A, lda, m0 + 0,   0, 0, 0);
    STAGE_HALF(SB, B, ldb, n0 + 0,   0, 0, 0);
    STAGE_HALF(SA, A, lda, m0 + 128, 0, 1, 0);
    STAGE_HALF(SB, B, ldb, n0 + 128, 0, 1, 0);
    STAGE_HALF(SA, A, lda, m0 + 0,   1, 0, 64);
    STAGE_HALF(SB, B, ldb, n0 + 0,   1, 0, 64);
    STAGE_HALF(SB, B, ldb, n0 + 128, 1, 1, 64);
    asm volatile("s_waitcnt vmcnt(6)" ::: "memory");
    __builtin_amdgcn_s_barrier();

    const int nt = K / 64;
    for (int t = 0; t < nt; ++t) {
        const int buf = t & 1, nbuf = buf ^ 1;
        const int k2 = (t + 2) * 64;
        // ---- p1: (0,0); stage A1(t+1) ----
        READ_A(0, buf);
        READ_B(0, buf);
        if (t + 1 < nt) STAGE_HALF(SA, A, lda, m0 + 128, nbuf, 1, (t + 1) * 64);
        MFMA_PHASE(0, 0);
        __builtin_amdgcn_s_barrier();
        // ---- p2: (0,1); stage A0(t+2) (slot's reads drained at p1) ----
        READ_B(1, buf);
        if (t + 2 < nt) STAGE_HALF(SA, A, lda, m0 + 0, buf, 0, k2);
        MFMA_PHASE(0, 1);
        __builtin_amdgcn_s_barrier();
        // ---- p3: (1,0); stage B0(t+2) (reads drained at p1) ----
        READ_A(1, buf);
        if (t + 2 < nt) STAGE_HALF(SB, B, ldb, n0 + 0, buf, 0, k2);
        MFMA_PHASE(1, 0);
        __builtin_amdgcn_s_barrier();
        // ---- p4: (1,1); stage B1(t+2) (reads drained at p2); vmcnt(6) ----
        if (t + 2 < nt) STAGE_HALF(SB, B, ldb, n0 + 128, buf, 1, k2);
        MFMA_PHASE(1, 1);
        asm volatile("s_waitcnt vmcnt(6)" ::: "memory");
        __builtin_amdgcn_s_barrier();
    }
#undef STAGE_HALF
#undef READ_A
#undef READ_B
#undef MFMA_PHASE

    const int cr4 = (lane >> 4) * 4, cc = lane & 15;
#pragma unroll
    for (int qm = 0; qm < 2; ++qm)
#pragma unroll
        for (int qn = 0; qn < 2; ++qn)
#pragma unroll
            for (int i = 0; i < 4; ++i)
#pragma unroll
                for (int j = 0; j < 2; ++j) {
                    const int col = n0 + qn * 128 + wc * 32 + j * 16 + cc;
#pragma unroll
                    for (int r = 0; r < 4; ++r) {
                        const int row = m0 + qm * 128 + wr * 64 + i * 16 + cr4 + r;
                        float v = acc[qm][qn][i][j][r];
                        if (GELU) v = gelu_exact(v);
                        CT* p = &C[(long)row * ldc + col];
                        if constexpr (sizeof(CT) == 2) *p = __float2bfloat16(v);
                        else *p = (CT)v;
                    }
                }
}

// ---------------------------------------------------------------------------
// 2-phase FF GEMM (round-10 verified) — used for FF2
// ---------------------------------------------------------------------------
template<int BM, int BN, int WM, int WN, typename CT, bool GELU>
__global__ __launch_bounds__(512, 4) void gemm_ff(
    const __hip_bfloat16* __restrict__ A1, int lda1, long az1,
    const __hip_bfloat16* __restrict__ A2, int lda2, long az2, int zsplit,
    const __hip_bfloat16* __restrict__ B, int ldb, long bz,
    CT* __restrict__ C, int ldc, long cz, int K)
{
    constexpr int WVM = BM / WM, WVN = BN / WN;
    constexpr int MR = WVM / 16, NR = WVN / 16;
    constexpr int ALOADS = (BM * 64) / (512 * 8);
    constexpr int BLOADS = (BN * 64) / (512 * 8);
    constexpr int LOADS  = ALOADS + BLOADS;

    __shared__ short As[2][BM * 64];
    __shared__ short Bs[2][BN * 64];

    const int tid = threadIdx.x;
    const int wv = tid >> 6, lane = tid & 63;
    const int wr = wv / WN, wc = wv % WN;

    const int gx = gridDim.x, gy = gridDim.y;
    const int nwg = gx * gy * gridDim.z;
    int lid = (blockIdx.z * gy + blockIdx.y) * gx + blockIdx.x;
    lid = (lid & 7) * (nwg >> 3) + (lid >> 3);
    const int bx = lid % gx, by = (lid / gx) % gy, bzz = lid / (gx * gy);

    const __hip_bfloat16* A;
    int lda;
    if (bzz < zsplit) { A = A1 + (long)bzz * az1;            lda = lda1; }
    else              { A = A2 + (long)(bzz - zsplit) * az2; lda = lda2; }
    B += (long)bzz * bz;  C += (long)bzz * cz;
    const int m0 = by * BM, n0 = bx * BN;

    f32x4 acc[MR][NR] = {};

    const int srow_a = tid >> 3, sslot = tid & 7;

#define STAGE(BUF, K0)                                                        \
    {                                                                         \
        _Pragma("unroll")                                                     \
        for (int i = 0; i < ALOADS; ++i) {                                    \
            const int row = srow_a + i * 64;                                  \
            const int gs  = sslot ^ (row & 7);                                \
            gload16(A + (long)(m0 + row) * lda + (K0) + gs * 8,               \
                    &As[BUF][(wv * 64 + i * 512) * 8]);                       \
        }                                                                     \
        _Pragma("unroll")                                                     \
        for (int i = 0; i < BLOADS; ++i) {                                    \
            const int row = srow_a + i * 64;                                  \
            const int gs  = sslot ^ (row & 7);                                \
            gload16(B + (long)(n0 + row) * ldb + (K0) + gs * 8,               \
                    &Bs[BUF][(wv * 64 + i * 512) * 8]);                       \
        }                                                                     \
    }

    const int fr = lane & 15, k4 = lane >> 4;
    const int nt = K / 64;
    int cur = 0;

    STAGE(0, 0);

    for (int t = 0; t < nt; ++t) {
        if (t + 1 < nt) {
            STAGE(cur ^ 1, (t + 1) * 64);
            asm volatile("s_waitcnt vmcnt(%0)\n\ts_barrier"
                         :: "n"(LOADS) : "memory");
        } else {
            asm volatile("s_waitcnt vmcnt(0)\n\ts_barrier" ::: "memory");
        }

#pragma unroll
        for (int ks = 0; ks < 2; ++ks) {
            bf16x8 af[MR], bf[NR];
#pragma unroll
            for (int i = 0; i < MR; ++i) {
                const int r = wr * WVM + i * 16 + fr;
                af[i] = *(const bf16x8*)&As[cur][r * 64 + ((ks * 4 + k4) ^ (r & 7)) * 8];
            }
#pragma unroll
            for (int j = 0; j < NR; ++j) {
                const int r = wc * WVN + j * 16 + fr;
                bf[j] = *(const bf16x8*)&Bs[cur][r * 64 + ((ks * 4 + k4) ^ (r & 7)) * 8];
            }
            __builtin_amdgcn_s_setprio(1);
#pragma unroll
            for (int i = 0; i < MR; ++i)
#pragma unroll
                for (int j = 0; j < NR; ++j)
                    acc[i][j] = __builtin_amdgcn_mfma_f32_16x16x32_bf16(
                        af[i], bf[j], acc[i][j], 0, 0, 0);
            __builtin_amdgcn_s_setprio(0);
        }
        asm volatile("s_waitcnt lgkmcnt(0)\n\ts_barrier" ::: "memory");
        cur ^= 1;
    }
#undef STAGE

    const int cr4 = (lane >> 4) * 4, cc = lane & 15;
#pragma unroll
    for (int i = 0; i < MR; ++i)
#pragma unroll
        for (int j = 0; j < NR; ++j) {
            const int col = n0 + wc * WVN + j * 16 + cc;
#pragma unroll
            for (int r = 0; r < 4; ++r) {
                const int row = m0 + wr * WVM + i * 16 + cr4 + r;
                float v = acc[i][j][r];
                if (GELU) v = gelu_exact(v);
                CT* p = &C[(long)row * ldc + col];
                if constexpr (sizeof(CT) == 2) *p = __float2bfloat16(v);
                else *p = (CT)v;
            }
        }
}

// ---------------------------------------------------------------------------
// Fused sim + softmax (round-9 verified)
// ---------------------------------------------------------------------------
__global__ __launch_bounds__(256) void simsm_kernel(
    const __hip_bfloat16* __restrict__ lev_bf, const float* __restrict__ invn,
    __hip_bfloat16* __restrict__ attn)
{
    __shared__ short As[64 * 32];
    __shared__ short Bs[256 * 32];
    __shared__ float redm[64][4];
    __shared__ float reds[64][4];

    const int tid = threadIdx.x;
    const int wv = tid >> 6, lane = tid & 63;
    const int z = blockIdx.y;
    const int b = z / 6, l = z - 6 * b;
    const __hip_bfloat16* base = lev_bf + (long)b * (N_ * L_ * D_) + (long)l * D_;
    const int m0 = blockIdx.x * 64;

    const int srow = tid >> 2, sslot = tid & 3;

    f32x4 acc[4][4] = {};
    const int fr = lane & 15, ksub = lane >> 4;

    for (int k0 = 0; k0 < 512; k0 += 32) {
        __syncthreads();
        {
            const int gs = sslot ^ ((srow >> 1) & 3);
            gload16(base + (long)(m0 + srow) * (L_ * D_) + k0 + gs * 8,
                    As + wv * 512);
        }
#pragma unroll
        for (int i = 0; i < 4; ++i) {
            const int row = srow + i * 64;
            const int gs  = sslot ^ ((row >> 1) & 3);
            gload16(base + (long)row * (L_ * D_) + k0 + gs * 8,
                    Bs + i * 2048 + wv * 512);
        }
        __syncthreads();

        bf16x8 af[4], bfr[4];
#pragma unroll
        for (int i = 0; i < 4; ++i) {
            const int ra = i * 16 + fr;
            af[i] = *(const bf16x8*)(As + ra * 32 + (ksub ^ ((ra >> 1) & 3)) * 8);
            const int rb = wv * 64 + i * 16 + fr;
            bfr[i] = *(const bf16x8*)(Bs + rb * 32 + (ksub ^ ((rb >> 1) & 3)) * 8);
        }
#pragma unroll
        for (int i = 0; i < 4; ++i)
#pragma unroll
            for (int j = 0; j < 4; ++j)
                acc[i][j] = __builtin_amdgcn_mfma_f32_16x16x32_bf16(
                    af[i], bfr[j], acc[i][j], 0, 0, 0);
    }

    const int cr4 = (lane >> 4) * 4, cc = lane & 15;
    const float sc = 0.044194173824159216f;

    float iv[4];
#pragma unroll
    for (int j = 0; j < 4; ++j)
        iv[j] = invn[((long)b * N_ + wv * 64 + j * 16 + cc) * L_ + l] * sc;
#pragma unroll
    for (int i = 0; i < 4; ++i)
#pragma unroll
        for (int j = 0; j < 4; ++j) {
            const int jg = wv * 64 + j * 16 + cc;
#pragma unroll
            for (int r = 0; r < 4; ++r) {
                const int ig = m0 + i * 16 + cr4 + r;
                float v = acc[i][j][r] * iv[j];
                if (ig == jg) v = -0.0005f;
                acc[i][j][r] = v;
            }
        }

    __syncthreads();

#pragma unroll
    for (int i = 0; i < 4; ++i)
#pragma unroll
        for (int r = 0; r < 4; ++r) {
            float m = fmaxf(fmaxf(acc[i][0][r], acc[i][1][r]),
                            fmaxf(acc[i][2][r], acc[i][3][r]));
#pragma unroll
            for (int o = 1; o < 16; o <<= 1) m = fmaxf(m, __shfl_xor(m, o));
            if (cc == 0) redm[i * 16 + cr4 + r][wv] = m;
        }
    __syncthreads();

#pragma unroll
    for (int i = 0; i < 4; ++i)
#pragma unroll
        for (int r = 0; r < 4; ++r) {
            const int rl = i * 16 + cr4 + r;
            const float m = fmaxf(fmaxf(redm[rl][0], redm[rl][1]),
                                  fmaxf(redm[rl][2], redm[rl][3]));
            float s = 0.f;
#pragma unroll
            for (int j = 0; j < 4; ++j) {
                const float e = expf(acc[i][j][r] - m);
                acc[i][j][r] = e;
                s += e;
            }
#pragma unroll
            for (int o = 1; o < 16; o <<= 1) s += __shfl_xor(s, o);
            if (cc == 0) reds[rl][wv] = s;
        }
    __syncthreads();

#pragma unroll
    for (int i = 0; i < 4; ++i)
#pragma unroll
        for (int r = 0; r < 4; ++r) {
            const int rl = i * 16 + cr4 + r;
            const float inv = 1.0f / (reds[rl][0] + reds[rl][1] +
                                      reds[rl][2] + reds[rl][3]);
            const long rowoff = ((long)z * N_ + m0 + rl) * N_;
#pragma unroll
            for (int j = 0; j < 4; ++j)
                attn[rowoff + wv * 64 + j * 16 + cc] =
                    __float2bfloat16(acc[i][j][r] * inv);
        }
}

// ---------------------------------------------------------------------------
// 128^2 MFMA kernels (patch embed, cons)
// ---------------------------------------------------------------------------
__device__ __forceinline__ void mfma_kloop(
    const __hip_bfloat16* __restrict__ A, int lda,
    const __hip_bfloat16* __restrict__ B, int ldb,
    int m0, int n0, int K, short* As, short* Bs,
    f32x4 acc[4][4], int wave, int lane)
{
    const int srow_in = lane >> 2;
    const int sslot   = lane & 3;
    const int wm = (wave >> 1) * 64, wn = (wave & 1) * 64;

    for (int k0 = 0; k0 < K; k0 += 32) {
        __syncthreads();
#pragma unroll
        for (int c = 0; c < 2; ++c) {
            const int rbase = c * 64 + wave * 16;
            const int row   = rbase + srow_in;
            const int gk    = sslot ^ ((row >> 1) & 3);
            gload16(A + (long)(m0 + row) * lda + k0 + gk * 8, As + rbase * 32);
            gload16(B + (long)(n0 + row) * ldb + k0 + gk * 8, Bs + rbase * 32);
        }
        __syncthreads();

        const int fr = lane & 15, ksub = lane >> 4;
        bf16x8 af[4], bfr[4];
#pragma unroll
        for (int i = 0; i < 4; ++i) {
            const int ra = wm + i * 16 + fr;
            af[i]  = *(const bf16x8*)(As + ra * 32 + (ksub ^ ((ra >> 1) & 3)) * 8);
            const int rb = wn + i * 16 + fr;
            bfr[i] = *(const bf16x8*)(Bs + rb * 32 + (ksub ^ ((rb >> 1) & 3)) * 8);
        }
#pragma unroll
        for (int i = 0; i < 4; ++i)
#pragma unroll
            for (int j = 0; j < 4; ++j)
                acc[i][j] = __builtin_amdgcn_mfma_f32_16x16x32_bf16(
                    af[i], bfr[j], acc[i][j], 0, 0, 0);
    }
}

template<typename CT, bool GELU>
__global__ __launch_bounds__(256) void gemm_mfma(
    const __hip_bfloat16* __restrict__ A, int lda, long az,
    const __hip_bfloat16* __restrict__ B, int ldb, long bz,
    CT* __restrict__ C, int ldc, long cz, int K,
    const float* __restrict__ bias)
{
    __shared__ short As[128 * 32];
    __shared__ short Bs[128 * 32];
    const int tid = threadIdx.x;
    const int wave = tid >> 6, lane = tid & 63;
    const int z = blockIdx.z;
    A += (long)z * az;  B += (long)z * bz;  C += (long)z * cz;
    const int m0 = blockIdx.y * 128, n0 = blockIdx.x * 128;
    const int wm = (wave >> 1) * 64, wn = (wave & 1) * 64;

    f32x4 acc[4][4] = {};
    mfma_kloop(A, lda, B, ldb, m0, n0, K, As, Bs, acc, wave, lane);

    const int cr = lane >> 4, cc = lane & 15;
#pragma unroll
    for (int j = 0; j < 4; ++j) {
        const int col = n0 + wn + j * 16 + cc;
        const float bv = bias ? bias[col] : 0.f;
#pragma unroll
        for (int i = 0; i < 4; ++i)
#pragma unroll
            for (int r = 0; r < 4; ++r) {
                const int row = m0 + wm + i * 16 + cr * 4 + r;
                float v = acc[i][j][r] + bv;
                if (GELU) v = gelu_exact(v);
                CT* p = &C[(long)row * ldc + col];
                if constexpr (sizeof(CT) == 2) *p = __float2bfloat16(v);
                else *p = (CT)v;
            }
    }
}

__global__ __launch_bounds__(256) void cons_mfma(
    const __hip_bfloat16* __restrict__ attn, const __hip_bfloat16* __restrict__ levT,
    __hip_bfloat16* __restrict__ cons)
{
    __shared__ short As[128 * 32];
    __shared__ short Bs[128 * 32];
    const int tid = threadIdx.x;
    const int wave = tid >> 6, lane = tid & 63;
    const int z = blockIdx.z;
    const int b = z / 6, l = z - 6 * b;
    const __hip_bfloat16* A = attn + (long)z * N_ * N_;
    const __hip_bfloat16* B = levT + (long)z * D_ * N_;
    __hip_bfloat16* C = cons + (long)b * (N_ * L_ * D_) + (long)l * D_;
    const int m0 = blockIdx.y * 128, n0 = blockIdx.x * 128;
    const int wm = (wave >> 1) * 64, wn = (wave & 1) * 64;

    f32x4 acc[4][4] = {};
    mfma_kloop(A, N_, B, N_, m0, n0, N_, As, Bs, acc, wave, lane);

    const int cr = lane >> 4, cc = lane & 15;
#pragma unroll
    for (int j = 0; j < 4; ++j) {
        const int col = n0 + wn + j * 16 + cc;
#pragma unroll
        for (int i = 0; i < 4; ++i)
#pragma unroll
            for (int r = 0; r < 4; ++r) {
                const int row = m0 + wm + i * 16 + cr * 4 + r;
                C[(long)row * (L_ * D_) + col] = __float2bfloat16(acc[i][j][r]);
            }
    }
}

// ---------------------------------------------------------------------------
// helper / elementwise kernels
// ---------------------------------------------------------------------------
__global__ __launch_bounds__(256) void transpose_to_bf16(
    const float* __restrict__ src, __hip_bfloat16* __restrict__ dst,
    int R, int Cc)
{
    __shared__ float t[32][33];
    const int zz = blockIdx.z;
    src += (long)zz * R * Cc;  dst += (long)zz * R * Cc;
    const int tx = threadIdx.x & 31, ty = threadIdx.x >> 5;
    const int c0 = blockIdx.x * 32, r0 = blockIdx.y * 32;
#pragma unroll
    for (int i = 0; i < 4; ++i)
        t[ty + i * 8][tx] = src[(long)(r0 + ty + i * 8) * Cc + c0 + tx];
    __syncthreads();
#pragma unroll
    for (int i = 0; i < 4; ++i)
        dst[(long)(c0 + ty + i * 8) * R + r0 + tx] = __float2bfloat16(t[tx][ty + i * 8]);
}

__global__ __launch_bounds__(256) void levT_kernel(
    const float* __restrict__ levels, __hip_bfloat16* __restrict__ levT)
{
    __shared__ float t[32][33];
    const int z = blockIdx.z;
    const int b = z / 6, l = z - 6 * b;
    const float* base = levels + (long)b * (N_ * L_ * D_) + (long)l * D_;
    const int tx = threadIdx.x & 31, ty = threadIdx.x >> 5;
    const int d0 = blockIdx.x * 32, j0 = blockIdx.y * 32;
#pragma unroll
    for (int i = 0; i < 4; ++i)
        t[ty + i * 8][tx] = base[(long)(j0 + ty + i * 8) * (L_ * D_) + d0 + tx];
    __syncthreads();
#pragma unroll
    for (int i = 0; i < 4; ++i)
        levT[(long)z * D_ * N_ + (long)(d0 + ty + i * 8) * N_ + j0 + tx] =
            __float2bfloat16(t[tx][ty + i * 8]);
}

__global__ __launch_bounds__(256) void invnorm_kernel(
    const float* __restrict__ levels, float* __restrict__ invn)
{
    const int wid = blockIdx.x * 4 + (threadIdx.x >> 6);
    const int lane = threadIdx.x & 63;
    const float* row = levels + (long)wid * 512;
    float s = 0.f;
#pragma unroll
    for (int k = lane * 4; k < 512; k += 256) {
        const float4 v = *(const float4*)&row[k];
        s += v.x * v.x + v.y * v.y + v.z * v.z + v.w * v.w;
    }
#pragma unroll
    for (int o = 1; o < 64; o <<= 1) s += __shfl_xor(s, o);
    if (lane == 0) invn[wid] = 1.0f / fmaxf(sqrtf(s), 1e-12f);
}

__global__ __launch_bounds__(256) void patchify_kernel(
    const float* __restrict__ img, __hip_bfloat16* __restrict__ Xp)
{
    const int t = blockIdx.x;
    const int b = t >> 8, n = t & 255;
    const int hh = n >> 4, ww = n & 15;
    for (int k = threadIdx.x; k < 608; k += 256) {
        float v = 0.f;
        if (k < 588) {
            const int c = k % 3;
            const int pj = (k / 3) % 14;
            const int pi = k / 42;
            v = img[(((long)b * 3 + c) * 224 + (hh * 14 + pi)) * 224 + (ww * 14 + pj)];
        }
        Xp[(long)t * 608 + k] = __float2bfloat16(v);
    }
}

__global__ __launch_bounds__(256) void wpT_kernel(
    const float* __restrict__ Wp, __hip_bfloat16* __restrict__ WpT)
{
    __shared__ float t[32][33];
    const int k0 = blockIdx.x * 32, d0 = blockIdx.y * 32;
    const int tx = threadIdx.x & 31, ty = threadIdx.x >> 5;
#pragma unroll
    for (int i = 0; i < 4; ++i) {
        const int k = k0 + ty + i * 8;
        t[ty + i * 8][tx] = (k < 588) ? Wp[(long)k * 512 + d0 + tx] : 0.f;
    }
    __syncthreads();
#pragma unroll
    for (int i = 0; i < 4; ++i)
        WpT[(long)(d0 + ty + i * 8) * 608 + k0 + tx] = __float2bfloat16(t[tx][ty + i * 8]);
}

__global__ __launch_bounds__(256) void init_levels_kernel(
    float* __restrict__ levels, const float* __restrict__ initlv)
{
    const long f = (long)blockIdx.x * 256 + threadIdx.x;
    const int d4 = f & 127;
    const int l = (int)((f >> 7) % 6);
    *(float4*)&levels[f * 4] = *(const float4*)&initlv[(long)l * 512 + d4 * 4];
}

__global__ __launch_bounds__(256) void lev_lp_init(
    const float* __restrict__ levels, const float* __restrict__ pos,
    __hip_bfloat16* __restrict__ lev_bf, __hip_bfloat16* __restrict__ lp_bf)
{
    const long f = (long)blockIdx.x * 256 + threadIdx.x;
    const int d4 = f & 127;
    const long tl = f >> 7;
    const int l = (int)(tl % 6);
    const long t = tl / 6;
    const float4 v = *(const float4*)&levels[f * 4];
    *(bf16x4s*)&lev_bf[f * 4] = to_bf4(v.x, v.y, v.z, v.w);
    if (l >= 1) {
        const float4 p = *(const float4*)&pos[(long)(t & 255) * 512 + d4 * 4];
        *(bf16x4s*)&lp_bf[((t * 5 + l - 1) * 512) + d4 * 4] =
            to_bf4(v.x + p.x, v.y + p.y, v.z + p.z, v.w + p.w);
    }
}

// one WAVE per (t,l) row: levels update + bf16 copies + invnorm for NEXT iter
__global__ __launch_bounds__(256) void update_kernel(
    float* __restrict__ levels, const float* __restrict__ tokens,
    const __hip_bfloat16* __restrict__ acc_bu, const __hip_bfloat16* __restrict__ acc_td,
    const __hip_bfloat16* __restrict__ cons, const float* __restrict__ pos,
    __hip_bfloat16* __restrict__ lev_bf, __hip_bfloat16* __restrict__ lp_bf,
    float* __restrict__ invn)
{
    const int wid = blockIdx.x * 4 + (threadIdx.x >> 6);   // row t*6+l
    const int lane = threadIdx.x & 63;
    const int l = wid % 6;
    const long t = wid / 6;
    const long rowoff = (long)wid * 512;

    float ss = 0.f;
#pragma unroll
    for (int half = 0; half < 2; ++half) {
        const int k = lane * 4 + half * 256;
        const long off = rowoff + k;
        float4 lev = *(const float4*)&levels[off];
        const ushort4 cu = *(const ushort4*)&cons[off];
        float4 ac;
        if (l == 0) {
            ac = *(const float4*)&tokens[t * 512 + k];
        } else {
            const ushort4 bu = *(const ushort4*)&acc_bu[((long)(l - 1) * NT_ + t) * 512 + k];
            ac = make_float4(bf_to_f(bu.x), bf_to_f(bu.y), bf_to_f(bu.z), bf_to_f(bu.w));
        }
        if (l < 5) {
            const ushort4 td = *(const ushort4*)&acc_td[((long)l * NT_ + t) * 512 + k];
            ac.x += bf_to_f(td.x); ac.y += bf_to_f(td.y);
            ac.z += bf_to_f(td.z); ac.w += bf_to_f(td.w);
        }
        lev.x = (lev.x + ac.x + bf_to_f(cu.x)) * 0.25f;
        lev.y = (lev.y + ac.y + bf_to_f(cu.y)) * 0.25f;
        lev.z = (lev.z + ac.z + bf_to_f(cu.z)) * 0.25f;
        lev.w = (lev.w + ac.w + bf_to_f(cu.w)) * 0.25f;
        *(float4*)&levels[off] = lev;
        *(bf16x4s*)&lev_bf[off] = to_bf4(lev.x, lev.y, lev.z, lev.w);
        if (l >= 1) {
            const float4 p = *(const float4*)&pos[(long)(t & 255) * 512 + k];
            *(bf16x4s*)&lp_bf[((t * 5 + l - 1) * 512) + k] =
                to_bf4(lev.x + p.x, lev.y + p.y, lev.z + p.z, lev.w + p.w);
        }
        ss += lev.x * lev.x + lev.y * lev.y + lev.z * lev.z + lev.w * lev.w;
    }
#pragma unroll
    for (int o = 1; o < 64; o <<= 1) ss += __shfl_xor(ss, o);
    if (lane == 0) invn[wid] = 1.0f / fmaxf(sqrtf(ss), 1e-12f);
}

extern "C" void kernel_launch(void* const* d_in, const int* in_sizes, int n_in,
                              void* d_out, int out_size, void* d_ws, size_t ws_size,
                              hipStream_t stream)
{
    const float* img    = (const float*)d_in[0];
    const float* Wp     = (const float*)d_in[1];
    const float* bp     = (const float*)d_in[2];
    const float* pos    = (const float*)d_in[3];
    const float* initlv = (const float*)d_in[4];
    const float* bu_in  = (const float*)d_in[5];
    const float* bu_out = (const float*)d_in[6];
    const float* td_in  = (const float*)d_in[7];
    const float* td_out = (const float*)d_in[8];

    float* levels = (float*)d_out;                 // [2048][6][512] fp32
    float* ws = (float*)d_ws;
    float* tokens  = ws;                           // 1,048,576 f
    __hip_bfloat16* acc_bu = (__hip_bfloat16*)(tokens + 1048576); // [5][2048][512] bf16
    __hip_bfloat16* acc_td = acc_bu + 5242880;                    // [5][2048][512] bf16
    __hip_bfloat16* h = acc_td + 5242880;          // [10][2048][2048] bf16
    float* invn    = (float*)(h + 41943040);       // 12,288 f
    __hip_bfloat16* lev_bf   = (__hip_bfloat16*)(invn + 12288);  // 6,291,456
    __hip_bfloat16* lp_bf    = lev_bf + 6291456;                 // 5,242,880
    __hip_bfloat16* wtin_all = lp_bf + 5242880;                  // 10,485,760 (bu 0-4, td 5-9)
    __hip_bfloat16* wtout_all= wtin_all + 10485760;              // 10,485,760

    __hip_bfloat16* cons_bf = h;                   // [2048][6][512] bf16 (h dead)
    __hip_bfloat16* levT_bf = lev_bf;              // [48][512][256] (alias)
    __hip_bfloat16* attn_bf = lp_bf;               // [48][256][256] (alias)
    __hip_bfloat16* Xp  = acc_bu;                  // [2048][608] (dead until FF2)
    __hip_bfloat16* WpT = Xp + 1245184;            // [512][608]

    init_levels_kernel<<<6144, 256, 0, stream>>>(levels, initlv);
    lev_lp_init<<<6144, 256, 0, stream>>>(levels, pos, lev_bf, lp_bf);
    invnorm_kernel<<<3072, 256, 0, stream>>>(levels, invn);   // iter-0 norms
    patchify_kernel<<<NT_, 256, 0, stream>>>(img, Xp);
    wpT_kernel<<<dim3(19, 16), 256, 0, stream>>>(Wp, WpT);
    gemm_mfma<float, false><<<dim3(4, 16, 1), 256, 0, stream>>>(
        Xp, 608, 0, WpT, 608, 0, tokens, 512, 0, 608, bp);
    // weights -> bf16, N x K transposed; bu at z=0..4, td at z=5..9
    transpose_to_bf16<<<dim3(64, 16, 5), 256, 0, stream>>>(bu_in,  wtin_all, 512, 2048);
    transpose_to_bf16<<<dim3(64, 16, 5), 256, 0, stream>>>(td_in,  wtin_all + 5242880, 512, 2048);
    transpose_to_bf16<<<dim3(16, 64, 5), 256, 0, stream>>>(bu_out, wtout_all, 2048, 512);
    transpose_to_bf16<<<dim3(16, 64, 5), 256, 0, stream>>>(td_out, wtout_all + 5242880, 2048, 512);

    for (int it = 0; it < 12; ++it) {
        // FF1 merged, 8-phase 256^2: z=0..4 bu (A=lev), z=5..9 td (A=lev+pos)
        gemm_ff8<__hip_bfloat16, true>
            <<<dim3(8, 8, 10), 512, 0, stream>>>(
            lev_bf, L_ * D_, 512,
            lp_bf, 5 * D_, 512, 5,
            wtin_all, D_, (long)HID_ * D_,
            h, HID_, (long)NT_ * HID_, D_);
        // FF2 merged (2-phase, round-10 verified): acc[z] = h[z] @ w_out[z]
        gemm_ff<128, 128, 2, 4, __hip_bfloat16, false>
            <<<dim3(4, 16, 10), 512, 0, stream>>>(
            h, HID_, (long)NT_ * HID_,
            h, HID_, (long)NT_ * HID_, 10,
            wtout_all, HID_, (long)D_ * HID_,
            acc_bu, D_, (long)NT_ * D_, HID_);

        simsm_kernel<<<dim3(4, 48), 256, 0, stream>>>(lev_bf, invn, attn_bf);
        levT_kernel<<<dim3(16, 8, 48), 256, 0, stream>>>(levels, levT_bf);
        cons_mfma<<<dim3(4, 2, 48), 256, 0, stream>>>(attn_bf, levT_bf, cons_bf);
        update_kernel<<<3072, 256, 0, stream>>>(levels, tokens, acc_bu, acc_td,
                                                cons_bf, pos, lev_bf, lp_bf, invn);
    }
}

// Round 12
// 2315.436 us; speedup vs baseline: 1.0712x; 1.0712x over previous
//
#include <hip/hip_runtime.h>
#include <hip/hip_bf16.h>
#include <math.h>

#define B_   8
#define N_   256
#define L_   6
#define D_   512
#define NT_  2048   // B_*N_
#define HID_ 2048

typedef __attribute__((ext_vector_type(4))) float f32x4;
typedef __attribute__((ext_vector_type(8))) short bf16x8;

struct bf16x4s { __hip_bfloat16 x, y, z, w; };

__device__ __forceinline__ bf16x4s to_bf4(float a, float b, float c, float d) {
    bf16x4s r;
    r.x = __float2bfloat16(a); r.y = __float2bfloat16(b);
    r.z = __float2bfloat16(c); r.w = __float2bfloat16(d);
    return r;
}

__device__ __forceinline__ float bf_to_f(unsigned short u) {
    union { unsigned int i; float f; } c;
    c.i = ((unsigned int)u) << 16;
    return c.f;
}

__device__ __forceinline__ void gload16(const void* g, void* l) {
    __builtin_amdgcn_global_load_lds(
        (const __attribute__((address_space(1))) int*)g,
        (__attribute__((address_space(3))) int*)l, 16, 0, 0);
}

// exact GELU via libm erff — measured faster than hand-rolled A&S (r7 vs r9)
__device__ __forceinline__ float gelu_exact(float v) {
    return 0.5f * v * (1.0f + erff(v * 0.70710678118654752f));
}

// ---------------------------------------------------------------------------
// FF GEMM (round-10 verified config): BM x BN tile, BK=64, 512 thr = 8 waves.
// Double-buffered LDS, counted-vmcnt pipeline. A-side z-split (lev vs
// lev+pos) -> bu+td in ONE z=10 dispatch. B pre-transposed (N x K).
// XOR swizzle slot ^= (row&7) on pre-swizzled global source + ds_read addr;
// gload_lds dest linear. XCD-aware bijective blockIdx swizzle (nwg%8==0).
// ---------------------------------------------------------------------------
template<int BM, int BN, int WM, int WN, typename CT, bool GELU>
__global__ __launch_bounds__(512, 4) void gemm_ff(
    const __hip_bfloat16* __restrict__ A1, int lda1, long az1,
    const __hip_bfloat16* __restrict__ A2, int lda2, long az2, int zsplit,
    const __hip_bfloat16* __restrict__ B, int ldb, long bz,
    CT* __restrict__ C, int ldc, long cz, int K)
{
    constexpr int WVM = BM / WM, WVN = BN / WN;
    constexpr int MR = WVM / 16, NR = WVN / 16;
    constexpr int ALOADS = (BM * 64) / (512 * 8);
    constexpr int BLOADS = (BN * 64) / (512 * 8);
    constexpr int LOADS  = ALOADS + BLOADS;

    __shared__ short As[2][BM * 64];
    __shared__ short Bs[2][BN * 64];

    const int tid = threadIdx.x;
    const int wv = tid >> 6, lane = tid & 63;
    const int wr = wv / WN, wc = wv % WN;

    const int gx = gridDim.x, gy = gridDim.y;
    const int nwg = gx * gy * gridDim.z;
    int lid = (blockIdx.z * gy + blockIdx.y) * gx + blockIdx.x;
    lid = (lid & 7) * (nwg >> 3) + (lid >> 3);
    const int bx = lid % gx, by = (lid / gx) % gy, bzz = lid / (gx * gy);

    const __hip_bfloat16* A;
    int lda;
    if (bzz < zsplit) { A = A1 + (long)bzz * az1;            lda = lda1; }
    else              { A = A2 + (long)(bzz - zsplit) * az2; lda = lda2; }
    B += (long)bzz * bz;  C += (long)bzz * cz;
    const int m0 = by * BM, n0 = bx * BN;

    f32x4 acc[MR][NR] = {};

    const int srow_a = tid >> 3, sslot = tid & 7;

#define STAGE(BUF, K0)                                                        \
    {                                                                         \
        _Pragma("unroll")                                                     \
        for (int i = 0; i < ALOADS; ++i) {                                    \
            const int row = srow_a + i * 64;                                  \
            const int gs  = sslot ^ (row & 7);                                \
            gload16(A + (long)(m0 + row) * lda + (K0) + gs * 8,               \
                    &As[BUF][(wv * 64 + i * 512) * 8]);                       \
        }                                                                     \
        _Pragma("unroll")                                                     \
        for (int i = 0; i < BLOADS; ++i) {                                    \
            const int row = srow_a + i * 64;                                  \
            const int gs  = sslot ^ (row & 7);                                \
            gload16(B + (long)(n0 + row) * ldb + (K0) + gs * 8,               \
                    &Bs[BUF][(wv * 64 + i * 512) * 8]);                       \
        }                                                                     \
    }

    const int fr = lane & 15, k4 = lane >> 4;
    const int nt = K / 64;
    int cur = 0;

    STAGE(0, 0);

    for (int t = 0; t < nt; ++t) {
        if (t + 1 < nt) {
            STAGE(cur ^ 1, (t + 1) * 64);
            asm volatile("s_waitcnt vmcnt(%0)\n\ts_barrier"
                         :: "n"(LOADS) : "memory");
        } else {
            asm volatile("s_waitcnt vmcnt(0)\n\ts_barrier" ::: "memory");
        }

#pragma unroll
        for (int ks = 0; ks < 2; ++ks) {
            bf16x8 af[MR], bf[NR];
#pragma unroll
            for (int i = 0; i < MR; ++i) {
                const int r = wr * WVM + i * 16 + fr;
                af[i] = *(const bf16x8*)&As[cur][r * 64 + ((ks * 4 + k4) ^ (r & 7)) * 8];
            }
#pragma unroll
            for (int j = 0; j < NR; ++j) {
                const int r = wc * WVN + j * 16 + fr;
                bf[j] = *(const bf16x8*)&Bs[cur][r * 64 + ((ks * 4 + k4) ^ (r & 7)) * 8];
            }
            __builtin_amdgcn_s_setprio(1);
#pragma unroll
            for (int i = 0; i < MR; ++i)
#pragma unroll
                for (int j = 0; j < NR; ++j)
                    acc[i][j] = __builtin_amdgcn_mfma_f32_16x16x32_bf16(
                        af[i], bf[j], acc[i][j], 0, 0, 0);
            __builtin_amdgcn_s_setprio(0);
        }
        asm volatile("s_waitcnt lgkmcnt(0)\n\ts_barrier" ::: "memory");
        cur ^= 1;
    }
#undef STAGE

    const int cr4 = (lane >> 4) * 4, cc = lane & 15;
#pragma unroll
    for (int i = 0; i < MR; ++i)
#pragma unroll
        for (int j = 0; j < NR; ++j) {
            const int col = n0 + wc * WVN + j * 16 + cc;
#pragma unroll
            for (int r = 0; r < 4; ++r) {
                const int row = m0 + wr * WVM + i * 16 + cr4 + r;
                float v = acc[i][j][r];
                if (GELU) v = gelu_exact(v);
                CT* p = &C[(long)row * ldc + col];
                if constexpr (sizeof(CT) == 2) *p = __float2bfloat16(v);
                else *p = (CT)v;
            }
        }
}

// ---------------------------------------------------------------------------
// Fused sim + softmax (round-9 verified)
// ---------------------------------------------------------------------------
__global__ __launch_bounds__(256) void simsm_kernel(
    const __hip_bfloat16* __restrict__ lev_bf, const float* __restrict__ invn,
    __hip_bfloat16* __restrict__ attn)
{
    __shared__ short As[64 * 32];
    __shared__ short Bs[256 * 32];
    __shared__ float redm[64][4];
    __shared__ float reds[64][4];

    const int tid = threadIdx.x;
    const int wv = tid >> 6, lane = tid & 63;
    const int z = blockIdx.y;
    const int b = z / 6, l = z - 6 * b;
    const __hip_bfloat16* base = lev_bf + (long)b * (N_ * L_ * D_) + (long)l * D_;
    const int m0 = blockIdx.x * 64;

    const int srow = tid >> 2, sslot = tid & 3;

    f32x4 acc[4][4] = {};
    const int fr = lane & 15, ksub = lane >> 4;

    for (int k0 = 0; k0 < 512; k0 += 32) {
        __syncthreads();
        {
            const int gs = sslot ^ ((srow >> 1) & 3);
            gload16(base + (long)(m0 + srow) * (L_ * D_) + k0 + gs * 8,
                    As + wv * 512);
        }
#pragma unroll
        for (int i = 0; i < 4; ++i) {
            const int row = srow + i * 64;
            const int gs  = sslot ^ ((row >> 1) & 3);
            gload16(base + (long)row * (L_ * D_) + k0 + gs * 8,
                    Bs + i * 2048 + wv * 512);
        }
        __syncthreads();

        bf16x8 af[4], bfr[4];
#pragma unroll
        for (int i = 0; i < 4; ++i) {
            const int ra = i * 16 + fr;
            af[i] = *(const bf16x8*)(As + ra * 32 + (ksub ^ ((ra >> 1) & 3)) * 8);
            const int rb = wv * 64 + i * 16 + fr;
            bfr[i] = *(const bf16x8*)(Bs + rb * 32 + (ksub ^ ((rb >> 1) & 3)) * 8);
        }
#pragma unroll
        for (int i = 0; i < 4; ++i)
#pragma unroll
            for (int j = 0; j < 4; ++j)
                acc[i][j] = __builtin_amdgcn_mfma_f32_16x16x32_bf16(
                    af[i], bfr[j], acc[i][j], 0, 0, 0);
    }

    const int cr4 = (lane >> 4) * 4, cc = lane & 15;
    const float sc = 0.044194173824159216f;

    float iv[4];
#pragma unroll
    for (int j = 0; j < 4; ++j)
        iv[j] = invn[((long)b * N_ + wv * 64 + j * 16 + cc) * L_ + l] * sc;
#pragma unroll
    for (int i = 0; i < 4; ++i)
#pragma unroll
        for (int j = 0; j < 4; ++j) {
            const int jg = wv * 64 + j * 16 + cc;
#pragma unroll
            for (int r = 0; r < 4; ++r) {
                const int ig = m0 + i * 16 + cr4 + r;
                float v = acc[i][j][r] * iv[j];
                if (ig == jg) v = -0.0005f;
                acc[i][j][r] = v;
            }
        }

    __syncthreads();

#pragma unroll
    for (int i = 0; i < 4; ++i)
#pragma unroll
        for (int r = 0; r < 4; ++r) {
            float m = fmaxf(fmaxf(acc[i][0][r], acc[i][1][r]),
                            fmaxf(acc[i][2][r], acc[i][3][r]));
#pragma unroll
            for (int o = 1; o < 16; o <<= 1) m = fmaxf(m, __shfl_xor(m, o));
            if (cc == 0) redm[i * 16 + cr4 + r][wv] = m;
        }
    __syncthreads();

#pragma unroll
    for (int i = 0; i < 4; ++i)
#pragma unroll
        for (int r = 0; r < 4; ++r) {
            const int rl = i * 16 + cr4 + r;
            const float m = fmaxf(fmaxf(redm[rl][0], redm[rl][1]),
                                  fmaxf(redm[rl][2], redm[rl][3]));
            float s = 0.f;
#pragma unroll
            for (int j = 0; j < 4; ++j) {
                const float e = expf(acc[i][j][r] - m);
                acc[i][j][r] = e;
                s += e;
            }
#pragma unroll
            for (int o = 1; o < 16; o <<= 1) s += __shfl_xor(s, o);
            if (cc == 0) reds[rl][wv] = s;
        }
    __syncthreads();

#pragma unroll
    for (int i = 0; i < 4; ++i)
#pragma unroll
        for (int r = 0; r < 4; ++r) {
            const int rl = i * 16 + cr4 + r;
            const float inv = 1.0f / (reds[rl][0] + reds[rl][1] +
                                      reds[rl][2] + reds[rl][3]);
            const long rowoff = ((long)z * N_ + m0 + rl) * N_;
#pragma unroll
            for (int j = 0; j < 4; ++j)
                attn[rowoff + wv * 64 + j * 16 + cc] =
                    __float2bfloat16(acc[i][j][r] * inv);
        }
}

// ---------------------------------------------------------------------------
// 128^2 MFMA kernels (patch embed, cons)
// ---------------------------------------------------------------------------
__device__ __forceinline__ void mfma_kloop(
    const __hip_bfloat16* __restrict__ A, int lda,
    const __hip_bfloat16* __restrict__ B, int ldb,
    int m0, int n0, int K, short* As, short* Bs,
    f32x4 acc[4][4], int wave, int lane)
{
    const int srow_in = lane >> 2;
    const int sslot   = lane & 3;
    const int wm = (wave >> 1) * 64, wn = (wave & 1) * 64;

    for (int k0 = 0; k0 < K; k0 += 32) {
        __syncthreads();
#pragma unroll
        for (int c = 0; c < 2; ++c) {
            const int rbase = c * 64 + wave * 16;
            const int row   = rbase + srow_in;
            const int gk    = sslot ^ ((row >> 1) & 3);
            gload16(A + (long)(m0 + row) * lda + k0 + gk * 8, As + rbase * 32);
            gload16(B + (long)(n0 + row) * ldb + k0 + gk * 8, Bs + rbase * 32);
        }
        __syncthreads();

        const int fr = lane & 15, ksub = lane >> 4;
        bf16x8 af[4], bfr[4];
#pragma unroll
        for (int i = 0; i < 4; ++i) {
            const int ra = wm + i * 16 + fr;
            af[i]  = *(const bf16x8*)(As + ra * 32 + (ksub ^ ((ra >> 1) & 3)) * 8);
            const int rb = wn + i * 16 + fr;
            bfr[i] = *(const bf16x8*)(Bs + rb * 32 + (ksub ^ ((rb >> 1) & 3)) * 8);
        }
#pragma unroll
        for (int i = 0; i < 4; ++i)
#pragma unroll
            for (int j = 0; j < 4; ++j)
                acc[i][j] = __builtin_amdgcn_mfma_f32_16x16x32_bf16(
                    af[i], bfr[j], acc[i][j], 0, 0, 0);
    }
}

template<typename CT, bool GELU>
__global__ __launch_bounds__(256) void gemm_mfma(
    const __hip_bfloat16* __restrict__ A, int lda, long az,
    const __hip_bfloat16* __restrict__ B, int ldb, long bz,
    CT* __restrict__ C, int ldc, long cz, int K,
    const float* __restrict__ bias)
{
    __shared__ short As[128 * 32];
    __shared__ short Bs[128 * 32];
    const int tid = threadIdx.x;
    const int wave = tid >> 6, lane = tid & 63;
    const int z = blockIdx.z;
    A += (long)z * az;  B += (long)z * bz;  C += (long)z * cz;
    const int m0 = blockIdx.y * 128, n0 = blockIdx.x * 128;
    const int wm = (wave >> 1) * 64, wn = (wave & 1) * 64;

    f32x4 acc[4][4] = {};
    mfma_kloop(A, lda, B, ldb, m0, n0, K, As, Bs, acc, wave, lane);

    const int cr = lane >> 4, cc = lane & 15;
#pragma unroll
    for (int j = 0; j < 4; ++j) {
        const int col = n0 + wn + j * 16 + cc;
        const float bv = bias ? bias[col] : 0.f;
#pragma unroll
        for (int i = 0; i < 4; ++i)
#pragma unroll
            for (int r = 0; r < 4; ++r) {
                const int row = m0 + wm + i * 16 + cr * 4 + r;
                float v = acc[i][j][r] + bv;
                if (GELU) v = gelu_exact(v);
                CT* p = &C[(long)row * ldc + col];
                if constexpr (sizeof(CT) == 2) *p = __float2bfloat16(v);
                else *p = (CT)v;
            }
    }
}

__global__ __launch_bounds__(256) void cons_mfma(
    const __hip_bfloat16* __restrict__ attn, const __hip_bfloat16* __restrict__ levT,
    __hip_bfloat16* __restrict__ cons)
{
    __shared__ short As[128 * 32];
    __shared__ short Bs[128 * 32];
    const int tid = threadIdx.x;
    const int wave = tid >> 6, lane = tid & 63;
    const int z = blockIdx.z;
    const int b = z / 6, l = z - 6 * b;
    const __hip_bfloat16* A = attn + (long)z * N_ * N_;
    const __hip_bfloat16* B = levT + (long)z * D_ * N_;
    __hip_bfloat16* C = cons + (long)b * (N_ * L_ * D_) + (long)l * D_;
    const int m0 = blockIdx.y * 128, n0 = blockIdx.x * 128;
    const int wm = (wave >> 1) * 64, wn = (wave & 1) * 64;

    f32x4 acc[4][4] = {};
    mfma_kloop(A, N_, B, N_, m0, n0, N_, As, Bs, acc, wave, lane);

    const int cr = lane >> 4, cc = lane & 15;
#pragma unroll
    for (int j = 0; j < 4; ++j) {
        const int col = n0 + wn + j * 16 + cc;
#pragma unroll
        for (int i = 0; i < 4; ++i)
#pragma unroll
            for (int r = 0; r < 4; ++r) {
                const int row = m0 + wm + i * 16 + cr * 4 + r;
                C[(long)row * (L_ * D_) + col] = __float2bfloat16(acc[i][j][r]);
            }
    }
}

// ---------------------------------------------------------------------------
// helper / elementwise kernels
// ---------------------------------------------------------------------------
__global__ __launch_bounds__(256) void transpose_to_bf16(
    const float* __restrict__ src, __hip_bfloat16* __restrict__ dst,
    int R, int Cc)
{
    __shared__ float t[32][33];
    const int zz = blockIdx.z;
    src += (long)zz * R * Cc;  dst += (long)zz * R * Cc;
    const int tx = threadIdx.x & 31, ty = threadIdx.x >> 5;
    const int c0 = blockIdx.x * 32, r0 = blockIdx.y * 32;
#pragma unroll
    for (int i = 0; i < 4; ++i)
        t[ty + i * 8][tx] = src[(long)(r0 + ty + i * 8) * Cc + c0 + tx];
    __syncthreads();
#pragma unroll
    for (int i = 0; i < 4; ++i)
        dst[(long)(c0 + ty + i * 8) * R + r0 + tx] = __float2bfloat16(t[tx][ty + i * 8]);
}

// levT from lev_bf (bit-identical to fp32 path: lev_bf == bf16(levels))
__global__ __launch_bounds__(256) void levT_kernel(
    const __hip_bfloat16* __restrict__ lev_bf, __hip_bfloat16* __restrict__ levT)
{
    __shared__ unsigned short t[32][33];
    const int z = blockIdx.z;
    const int b = z / 6, l = z - 6 * b;
    const __hip_bfloat16* base = lev_bf + (long)b * (N_ * L_ * D_) + (long)l * D_;
    const int tx = threadIdx.x & 31, ty = threadIdx.x >> 5;
    const int d0 = blockIdx.x * 32, j0 = blockIdx.y * 32;
#pragma unroll
    for (int i = 0; i < 4; ++i)
        t[ty + i * 8][tx] = ((const unsigned short*)base)[(long)(j0 + ty + i * 8) * (L_ * D_) + d0 + tx];
    __syncthreads();
#pragma unroll
    for (int i = 0; i < 4; ++i)
        ((unsigned short*)levT)[(long)z * D_ * N_ + (long)(d0 + ty + i * 8) * N_ + j0 + tx] =
            t[tx][ty + i * 8];
}

__global__ __launch_bounds__(256) void invnorm_kernel(
    const float* __restrict__ levels, float* __restrict__ invn)
{
    const int wid = blockIdx.x * 4 + (threadIdx.x >> 6);
    const int lane = threadIdx.x & 63;
    const float* row = levels + (long)wid * 512;
    float s = 0.f;
#pragma unroll
    for (int k = lane * 4; k < 512; k += 256) {
        const float4 v = *(const float4*)&row[k];
        s += v.x * v.x + v.y * v.y + v.z * v.z + v.w * v.w;
    }
#pragma unroll
    for (int o = 1; o < 64; o <<= 1) s += __shfl_xor(s, o);
    if (lane == 0) invn[wid] = 1.0f / fmaxf(sqrtf(s), 1e-12f);
}

__global__ __launch_bounds__(256) void patchify_kernel(
    const float* __restrict__ img, __hip_bfloat16* __restrict__ Xp)
{
    const int t = blockIdx.x;
    const int b = t >> 8, n = t & 255;
    const int hh = n >> 4, ww = n & 15;
    for (int k = threadIdx.x; k < 608; k += 256) {
        float v = 0.f;
        if (k < 588) {
            const int c = k % 3;
            const int pj = (k / 3) % 14;
            const int pi = k / 42;
            v = img[(((long)b * 3 + c) * 224 + (hh * 14 + pi)) * 224 + (ww * 14 + pj)];
        }
        Xp[(long)t * 608 + k] = __float2bfloat16(v);
    }
}

__global__ __launch_bounds__(256) void wpT_kernel(
    const float* __restrict__ Wp, __hip_bfloat16* __restrict__ WpT)
{
    __shared__ float t[32][33];
    const int k0 = blockIdx.x * 32, d0 = blockIdx.y * 32;
    const int tx = threadIdx.x & 31, ty = threadIdx.x >> 5;
#pragma unroll
    for (int i = 0; i < 4; ++i) {
        const int k = k0 + ty + i * 8;
        t[ty + i * 8][tx] = (k < 588) ? Wp[(long)k * 512 + d0 + tx] : 0.f;
    }
    __syncthreads();
#pragma unroll
    for (int i = 0; i < 4; ++i)
        WpT[(long)(d0 + ty + i * 8) * 608 + k0 + tx] = __float2bfloat16(t[tx][ty + i * 8]);
}

__global__ __launch_bounds__(256) void init_levels_kernel(
    float* __restrict__ levels, const float* __restrict__ initlv)
{
    const long f = (long)blockIdx.x * 256 + threadIdx.x;
    const int d4 = f & 127;
    const int l = (int)((f >> 7) % 6);
    *(float4*)&levels[f * 4] = *(const float4*)&initlv[(long)l * 512 + d4 * 4];
}

__global__ __launch_bounds__(256) void lev_lp_init(
    const float* __restrict__ levels, const float* __restrict__ pos,
    __hip_bfloat16* __restrict__ lev_bf, __hip_bfloat16* __restrict__ lp_bf)
{
    const long f = (long)blockIdx.x * 256 + threadIdx.x;
    const int d4 = f & 127;
    const long tl = f >> 7;
    const int l = (int)(tl % 6);
    const long t = tl / 6;
    const float4 v = *(const float4*)&levels[f * 4];
    *(bf16x4s*)&lev_bf[f * 4] = to_bf4(v.x, v.y, v.z, v.w);
    if (l >= 1) {
        const float4 p = *(const float4*)&pos[(long)(t & 255) * 512 + d4 * 4];
        *(bf16x4s*)&lp_bf[((t * 5 + l - 1) * 512) + d4 * 4] =
            to_bf4(v.x + p.x, v.y + p.y, v.z + p.z, v.w + p.w);
    }
}

// one WAVE per (t,l) row: levels update + bf16 copies + invnorm for NEXT iter
__global__ __launch_bounds__(256) void update_kernel(
    float* __restrict__ levels, const float* __restrict__ tokens,
    const __hip_bfloat16* __restrict__ acc_bu, const __hip_bfloat16* __restrict__ acc_td,
    const __hip_bfloat16* __restrict__ cons, const float* __restrict__ pos,
    __hip_bfloat16* __restrict__ lev_bf, __hip_bfloat16* __restrict__ lp_bf,
    float* __restrict__ invn)
{
    const int wid = blockIdx.x * 4 + (threadIdx.x >> 6);   // row t*6+l
    const int lane = threadIdx.x & 63;
    const int l = wid % 6;
    const long t = wid / 6;
    const long rowoff = (long)wid * 512;

    float ss = 0.f;
#pragma unroll
    for (int half = 0; half < 2; ++half) {
        const int k = lane * 4 + half * 256;
        const long off = rowoff + k;
        float4 lev = *(const float4*)&levels[off];
        const ushort4 cu = *(const ushort4*)&cons[off];
        float4 ac;
        if (l == 0) {
            ac = *(const float4*)&tokens[t * 512 + k];
        } else {
            const ushort4 bu = *(const ushort4*)&acc_bu[((long)(l - 1) * NT_ + t) * 512 + k];
            ac = make_float4(bf_to_f(bu.x), bf_to_f(bu.y), bf_to_f(bu.z), bf_to_f(bu.w));
        }
        if (l < 5) {
            const ushort4 td = *(const ushort4*)&acc_td[((long)l * NT_ + t) * 512 + k];
            ac.x += bf_to_f(td.x); ac.y += bf_to_f(td.y);
            ac.z += bf_to_f(td.z); ac.w += bf_to_f(td.w);
        }
        lev.x = (lev.x + ac.x + bf_to_f(cu.x)) * 0.25f;
        lev.y = (lev.y + ac.y + bf_to_f(cu.y)) * 0.25f;
        lev.z = (lev.z + ac.z + bf_to_f(cu.z)) * 0.25f;
        lev.w = (lev.w + ac.w + bf_to_f(cu.w)) * 0.25f;
        *(float4*)&levels[off] = lev;
        *(bf16x4s*)&lev_bf[off] = to_bf4(lev.x, lev.y, lev.z, lev.w);
        if (l >= 1) {
            const float4 p = *(const float4*)&pos[(long)(t & 255) * 512 + k];
            *(bf16x4s*)&lp_bf[((t * 5 + l - 1) * 512) + k] =
                to_bf4(lev.x + p.x, lev.y + p.y, lev.z + p.z, lev.w + p.w);
        }
        ss += lev.x * lev.x + lev.y * lev.y + lev.z * lev.z + lev.w * lev.w;
    }
#pragma unroll
    for (int o = 1; o < 64; o <<= 1) ss += __shfl_xor(ss, o);
    if (lane == 0) invn[wid] = 1.0f / fmaxf(sqrtf(ss), 1e-12f);
}

extern "C" void kernel_launch(void* const* d_in, const int* in_sizes, int n_in,
                              void* d_out, int out_size, void* d_ws, size_t ws_size,
                              hipStream_t stream)
{
    const float* img    = (const float*)d_in[0];
    const float* Wp     = (const float*)d_in[1];
    const float* bp     = (const float*)d_in[2];
    const float* pos    = (const float*)d_in[3];
    const float* initlv = (const float*)d_in[4];
    const float* bu_in  = (const float*)d_in[5];
    const float* bu_out = (const float*)d_in[6];
    const float* td_in  = (const float*)d_in[7];
    const float* td_out = (const float*)d_in[8];

    float* levels = (float*)d_out;                 // [2048][6][512] fp32
    float* ws = (float*)d_ws;
    float* tokens  = ws;                           // 1,048,576 f
    __hip_bfloat16* acc_bu = (__hip_bfloat16*)(tokens + 1048576); // [5][2048][512] bf16
    __hip_bfloat16* acc_td = acc_bu + 5242880;                    // [5][2048][512] bf16
    __hip_bfloat16* h = acc_td + 5242880;          // [10][2048][2048] bf16
    float* invn    = (float*)(h + 41943040);       // 12,288 f
    __hip_bfloat16* lev_bf   = (__hip_bfloat16*)(invn + 12288);  // 6,291,456
    __hip_bfloat16* lp_bf    = lev_bf + 6291456;                 // 5,242,880
    __hip_bfloat16* wtin_all = lp_bf + 5242880;                  // 10,485,760 (bu 0-4, td 5-9)
    __hip_bfloat16* wtout_all= wtin_all + 10485760;              // 10,485,760

    __hip_bfloat16* cons_bf = h;                   // [2048][6][512] bf16 (h dead)
    __hip_bfloat16* levT_bf = lev_bf + 0;          // NOTE: separate buffer now needed?
    // levT aliases lev_bf was only safe when levT read fp32 levels. Now levT
    // READS lev_bf while writing levT — overlap would race. Place levT after
    // cons_bf inside h (h is [10]*8MB = 80MB; cons_bf uses 12MB).
    levT_bf = h + 6291456;                         // [48][512][256] bf16 (h dead region)
    __hip_bfloat16* attn_bf = lp_bf;               // [48][256][256] (alias, lp_bf dead)
    __hip_bfloat16* Xp  = acc_bu;                  // [2048][608] (dead until FF2)
    __hip_bfloat16* WpT = Xp + 1245184;            // [512][608]

    init_levels_kernel<<<6144, 256, 0, stream>>>(levels, initlv);
    lev_lp_init<<<6144, 256, 0, stream>>>(levels, pos, lev_bf, lp_bf);
    invnorm_kernel<<<3072, 256, 0, stream>>>(levels, invn);   // iter-0 norms
    patchify_kernel<<<NT_, 256, 0, stream>>>(img, Xp);
    wpT_kernel<<<dim3(19, 16), 256, 0, stream>>>(Wp, WpT);
    gemm_mfma<float, false><<<dim3(4, 16, 1), 256, 0, stream>>>(
        Xp, 608, 0, WpT, 608, 0, tokens, 512, 0, 608, bp);
    // weights -> bf16, N x K transposed; bu at z=0..4, td at z=5..9
    transpose_to_bf16<<<dim3(64, 16, 5), 256, 0, stream>>>(bu_in,  wtin_all, 512, 2048);
    transpose_to_bf16<<<dim3(64, 16, 5), 256, 0, stream>>>(td_in,  wtin_all + 5242880, 512, 2048);
    transpose_to_bf16<<<dim3(16, 64, 5), 256, 0, stream>>>(bu_out, wtout_all, 2048, 512);
    transpose_to_bf16<<<dim3(16, 64, 5), 256, 0, stream>>>(td_out, wtout_all + 5242880, 2048, 512);

    for (int it = 0; it < 12; ++it) {
        // FF1 merged (2-phase, round-10 verified): z=0..4 bu, z=5..9 td
        gemm_ff<128, 128, 2, 4, __hip_bfloat16, true>
            <<<dim3(16, 16, 10), 512, 0, stream>>>(
            lev_bf, L_ * D_, 512,
            lp_bf, 5 * D_, 512, 5,
            wtin_all, D_, (long)HID_ * D_,
            h, HID_, (long)NT_ * HID_, D_);
        // FF2 merged (2-phase, round-10 verified): acc[z] = h[z] @ w_out[z]
        gemm_ff<128, 128, 2, 4, __hip_bfloat16, false>
            <<<dim3(4, 16, 10), 512, 0, stream>>>(
            h, HID_, (long)NT_ * HID_,
            h, HID_, (long)NT_ * HID_, 10,
            wtout_all, HID_, (long)D_ * HID_,
            acc_bu, D_, (long)NT_ * D_, HID_);

        simsm_kernel<<<dim3(4, 48), 256, 0, stream>>>(lev_bf, invn, attn_bf);
        levT_kernel<<<dim3(16, 8, 48), 256, 0, stream>>>(lev_bf, levT_bf);
        cons_mfma<<<dim3(4, 2, 48), 256, 0, stream>>>(attn_bf, levT_bf, cons_bf);
        update_kernel<<<3072, 256, 0, stream>>>(levels, tokens, acc_bu, acc_td,
                                                cons_bf, pos, lev_bf, lp_bf, invn);
    }
}